// Round 12
// baseline (84.410 us; speedup 1.0000x reference)
//
#include <hip/hip_runtime.h>

// Problem constants (from reference setup_inputs).
constexpr int B = 8;
constexpr int N = 16384;
constexpr int M = 1024;
constexpr int C = 256;

typedef float vf16 __attribute__((ext_vector_type(16)));

// One block = ONE wave = 64 points (lane l -> point nbase+l). 2048 blocks.
// No LDS, no barriers, no merge: each wave scans ALL 1024 candidates via the
// SMEM pipe (s_load_dwordx16 x3 per 16-candidate chunk -> SGPRs; VALU reads
// them as src0). Selection is bit-exact vs the reference:
//   d = (dx*dx + dy*dy) + dz*dz, separately rounded ((c-x) negation squares
//   identically); strict-< ladder = top_k lowest-index tie-break.
// Phase 2: per point p, v_readlane broadcasts lane p's {meta, w0, w1, w2};
// lane l gathers/stores channel-quad l (coalesced 1KB rows). Waves drift
// freely so scan VALU of some waves overlaps gather/store VMEM of others.
// XCD swizzle: batch = blk & 7 pins each batch's 1MB feats to one XCD's L2.
__global__ __launch_bounds__(64, 4) void upsample_idw_kernel(
    const float* __restrict__ xyz,          // [B,N,3]
    const float* __restrict__ sxyz,         // [B,M,3]
    const float* __restrict__ feats,        // [B,M,C]
    const int*   __restrict__ masks,        // [B,N]
    float*       __restrict__ out)          // [B,N,C]
{
    const int l   = threadIdx.x;            // lane = point within block
    const int blk = blockIdx.x;
    const int b     = blk & 7;              // batch == XCD (round-robin dispatch)
    const int nbase = (blk >> 3) << 6;      // first point of this block

    // Own point coords + mask.
    const float* xp = xyz + ((size_t)b * N + nbase + l) * 3;
    const float x = xp[0], y = xp[1], z = xp[2];
    const int valid = masks[(size_t)b * N + nbase + l] ? 1 : 0;

    // BLOCK-uniform batch base (SGPR pair for s_load).
    const float* bbase = sxyz + (size_t)b * (M * 3);

    float d0 = __builtin_inff(), d1 = __builtin_inff(), d2 = __builtin_inff();
    int   i0 = 0, i1 = 0, i2 = 0;

    for (int ch = 0; ch < 64; ++ch) {       // 64 chunks x 16 candidates = 1024
        vf16 ca, cb, cc;                    // 48 floats = 16 candidates in SGPRs
        const int off = ch * 192;           // uniform byte offset
        asm volatile(
            "s_load_dwordx16 %0, %3, %4\n\t"
            "s_load_dwordx16 %1, %3, %4 offset:64\n\t"
            "s_load_dwordx16 %2, %3, %4 offset:128\n\t"
            "s_waitcnt lgkmcnt(0)"
            : "=&s"(ca), "=&s"(cb), "=&s"(cc)
            : "s"(bbase), "s"(off));
        #pragma unroll
        for (int j = 0; j < 16; ++j) {
            const int f0 = 3 * j, f1 = 3 * j + 1, f2 = 3 * j + 2;
            const float cx = (f0 < 16) ? ca[f0 & 15] : (f0 < 32) ? cb[f0 & 15] : cc[f0 & 15];
            const float cy = (f1 < 16) ? ca[f1 & 15] : (f1 < 32) ? cb[f1 & 15] : cc[f1 & 15];
            const float cz = (f2 < 16) ? ca[f2 & 15] : (f2 < 32) ? cb[f2 & 15] : cc[f2 & 15];
            // (c - x): negated dx, identical after squaring (IEEE exact).
            const float dx = __fsub_rn(cx, x);
            const float dy = __fsub_rn(cy, y);
            const float dz = __fsub_rn(cz, z);
            const float d  = __fadd_rn(__fadd_rn(__fmul_rn(dx, dx), __fmul_rn(dy, dy)),
                                       __fmul_rn(dz, dz));
            const int m = ch * 16 + j;      // uniform value
            // Strict < keeps earlier (lower) index on ties (matches top_k).
            const bool lt0 = d < d0, lt1 = d < d1, lt2 = d < d2;
            i2 = lt1 ? i1 : (lt2 ? m : i2);
            i1 = lt0 ? i0 : (lt1 ? m : i1);
            i0 = lt0 ? m  : i0;
            // Exact value ladder: min + 2x med3 (selection only, no rounding).
            const float nd2 = __builtin_amdgcn_fmed3f(d1, d2, d);
            const float nd1 = __builtin_amdgcn_fmed3f(d0, d1, d);
            d2 = nd2; d1 = nd1; d0 = fminf(d0, d);
        }
    }

    // IDW weights (P=2), per lane for its own point.
    const float m0 = fmaxf(d0, 1e-10f);
    const float m1 = fmaxf(d1, 1e-10f);
    const float m2 = fmaxf(d2, 1e-10f);
    float w0 = 1.0f / (m0 * m0 + 1e-10f);
    float w1 = 1.0f / (m1 * m1 + 1e-10f);
    float w2 = 1.0f / (m2 * m2 + 1e-10f);
    const float scale = valid ? (1.0f / (w0 + w1 + w2)) : 0.0f;
    w0 *= scale; w1 *= scale; w2 *= scale;
    // Pack indices + valid: j0 | j1<<10 | j2<<20 | valid<<30 (j < 1024).
    const unsigned meta = (unsigned)i0 | ((unsigned)i1 << 10) |
                          ((unsigned)i2 << 20) | ((unsigned)valid << 30);

    // ---- Phase 2: per point p, readlane broadcast + coalesced gather/store ----
    const float4* Fb4 = (const float4*)(feats + (size_t)b * (M * C));
    float4* op4 = (float4*)(out + (((size_t)b * N + nbase) * C));

    #pragma unroll 2
    for (int p = 0; p < 64; ++p) {
        const unsigned mt = (unsigned)__builtin_amdgcn_readlane((int)meta, p);
        float4 acc = make_float4(0.f, 0.f, 0.f, 0.f);
        if (mt >> 30) {                      // wave-uniform branch (SGPR)
            const int g0 = (int)(mt & 1023u);
            const int g1 = (int)((mt >> 10) & 1023u);
            const int g2 = (int)((mt >> 20) & 1023u);
            const float u0 = __uint_as_float((unsigned)
                __builtin_amdgcn_readlane((int)__float_as_uint(w0), p));
            const float u1 = __uint_as_float((unsigned)
                __builtin_amdgcn_readlane((int)__float_as_uint(w1), p));
            const float u2 = __uint_as_float((unsigned)
                __builtin_amdgcn_readlane((int)__float_as_uint(w2), p));
            const float4 f0 = Fb4[g0 * 64 + l];
            const float4 f1 = Fb4[g1 * 64 + l];
            const float4 f2 = Fb4[g2 * 64 + l];
            acc.x = fmaf(u2, f2.x, fmaf(u1, f1.x, u0 * f0.x));
            acc.y = fmaf(u2, f2.y, fmaf(u1, f1.y, u0 * f0.y));
            acc.z = fmaf(u2, f2.z, fmaf(u1, f1.z, u0 * f0.z));
            acc.w = fmaf(u2, f2.w, fmaf(u1, f1.w, u0 * f0.w));
        }
        op4[p * 64 + l] = acc;
    }
}

extern "C" void kernel_launch(void* const* d_in, const int* in_sizes, int n_in,
                              void* d_out, int out_size, void* d_ws, size_t ws_size,
                              hipStream_t stream) {
    const float* xyz   = (const float*)d_in[0];
    const float* sxyz  = (const float*)d_in[1];
    const float* feats = (const float*)d_in[2];
    const int*   masks = (const int*)d_in[3];
    float*       out   = (float*)d_out;

    dim3 grid(B * N / 64);    // 2048 one-wave blocks
    dim3 block(64);
    hipLaunchKernelGGL(upsample_idw_kernel, grid, block, 0, stream,
                       xyz, sxyz, feats, masks, out);
}

// Round 13
// 78.319 us; speedup vs baseline: 1.0778x; 1.0778x over previous
//
#include <hip/hip_runtime.h>

// Problem constants (from reference setup_inputs).
constexpr int B = 8;
constexpr int N = 16384;
constexpr int M = 1024;
constexpr int C = 256;

typedef float vf8 __attribute__((ext_vector_type(8)));

// Block = 512 threads = 8 waves, owns TWO 64-point tiles; grid 1024 ->
// 4 blocks/CU x 8 waves = 32 waves/CU (full). Pipeline per block:
//   scan(A) -> merge(A) -> [p2(A) gathers/stores interleaved with scan(B)]
//   -> merge(B) -> p2(B).
// Scan: wave w covers candidates [w*128,(w+1)*128) via the SMEM pipe
// (s_load_dwordx8 x3 per 8-candidate chunk -> 24 SGPRs; VALU reads as src0).
// Selection is bit-exact vs the reference: d = (dx*dx+dy*dy)+dz*dz with
// separately-rounded f32 ops ((c-x) squares identically to (x-c)); strict-<
// ladder + u64 (dist<<32|idx) merge = top_k lowest-index tie-break.
// Fused p2: issue-early/consume-late — row-group gathers issue, then TWO scan
// chunks (~1200cy ladder VALU) run while gathers are in flight, then the fma+
// store consumes them. Stores overlap scan VALU instead of serializing after.
// XCD swizzle: batch = blk & 7 pins each batch's 1MB feats to one XCD's L2.
__global__ __launch_bounds__(512, 8) void upsample_idw_kernel(
    const float* __restrict__ xyz,          // [B,N,3]
    const float* __restrict__ sxyz,         // [B,M,3]
    const float* __restrict__ feats,        // [B,M,C]
    const int*   __restrict__ masks,        // [B,N]
    float*       __restrict__ out)          // [B,N,C]
{
    const int tid = threadIdx.x;
    const int w   = tid >> 6;               // wave id (0..7) = candidate eighth
    const int l   = tid & 63;               // lane = point within tile
    const int blk = blockIdx.x;
    const int b     = blk & 7;              // batch == XCD (round-robin dispatch)
    const int nbase = (blk >> 3) << 7;      // first point (128 per block)

    // Keys: [point][w*3+s], row pitch 25 u64 (200B) -> 16-bank spread (4-way).
    __shared__ unsigned long long s_key[64][25];     // 12.8KB (reused per tile)
    __shared__ float s_wt[2][64][3];                 // 1.5KB
    __shared__ int   s_jv[2][64][4];                 // 2KB (j0,j1,j2,valid)

    // BLOCK-uniform batch base (SGPR pair); wave byte-offset via readfirstlane.
    const float* bbase = sxyz + (size_t)b * (M * 3);
    const int qoff = __builtin_amdgcn_readfirstlane((tid >> 6) * 1536); // 128 cands * 12B

    // Point coords for both tiles (lane l -> point tilebase + l).
    const float* xp0 = xyz + ((size_t)b * N + nbase + l) * 3;
    const float* xp1 = xyz + ((size_t)b * N + nbase + 64 + l) * 3;
    const float x0 = xp0[0], y0 = xp0[1], z0 = xp0[2];
    const float x1 = xp1[0], y1 = xp1[1], z1 = xp1[2];

    const float4* Fb4 = (const float4*)(feats + (size_t)b * (M * C));
    float4* op4_0 = (float4*)(out + (((size_t)b * N + nbase) * C));
    float4* op4_1 = (float4*)(out + (((size_t)b * N + nbase + 64) * C));

    // Ladder state (reused for tile A then tile B).
    float d0, d1, d2;
    int   i0, i1, i2;
    auto reset_ladder = [&]() {
        d0 = d1 = d2 = __builtin_inff();
        i0 = i1 = i2 = 0;
    };

    // One 8-candidate SMEM chunk through the bit-exact ladder.
    auto scan_chunk = [&](int ch, float px, float py, float pz) {
        vf8 ca, cb, cc;                     // 24 floats = 8 candidates in SGPRs
        const int off = qoff + ch * 96;
        asm volatile(
            "s_load_dwordx8 %0, %3, %4\n\t"
            "s_load_dwordx8 %1, %3, %4 offset:32\n\t"
            "s_load_dwordx8 %2, %3, %4 offset:64\n\t"
            "s_waitcnt lgkmcnt(0)"
            : "=&s"(ca), "=&s"(cb), "=&s"(cc)
            : "s"(bbase), "s"(off));
        #pragma unroll
        for (int j = 0; j < 8; ++j) {
            const int f0 = 3 * j, f1 = 3 * j + 1, f2 = 3 * j + 2;
            const float cx = (f0 < 8) ? ca[f0 & 7] : (f0 < 16) ? cb[f0 & 7] : cc[f0 & 7];
            const float cy = (f1 < 8) ? ca[f1 & 7] : (f1 < 16) ? cb[f1 & 7] : cc[f1 & 7];
            const float cz = (f2 < 8) ? ca[f2 & 7] : (f2 < 16) ? cb[f2 & 7] : cc[f2 & 7];
            // (c - x): negated dx, identical after squaring (IEEE exact).
            const float dx = __fsub_rn(cx, px);
            const float dy = __fsub_rn(cy, py);
            const float dz = __fsub_rn(cz, pz);
            const float d  = __fadd_rn(__fadd_rn(__fmul_rn(dx, dx), __fmul_rn(dy, dy)),
                                       __fmul_rn(dz, dz));
            const int m = ch * 8 + j;       // uniform value
            // Strict < keeps earlier (lower) index on ties (matches top_k).
            const bool lt0 = d < d0, lt1 = d < d1, lt2 = d < d2;
            i2 = lt1 ? i1 : (lt2 ? m : i2);
            i1 = lt0 ? i0 : (lt1 ? m : i1);
            i0 = lt0 ? m  : i0;
            // Exact value ladder: min + 2x med3 (selection only, no rounding).
            const float nd2 = __builtin_amdgcn_fmed3f(d1, d2, d);
            const float nd1 = __builtin_amdgcn_fmed3f(d0, d1, d);
            d2 = nd2; d1 = nd1; d0 = fminf(d0, d);
        }
    };

    auto store_keys = [&]() {
        const unsigned base = (unsigned)(w * 128);
        s_key[l][w * 3 + 0] = ((unsigned long long)__float_as_uint(d0) << 32) | (base + (unsigned)i0);
        s_key[l][w * 3 + 1] = ((unsigned long long)__float_as_uint(d1) << 32) | (base + (unsigned)i1);
        s_key[l][w * 3 + 2] = ((unsigned long long)__float_as_uint(d2) << 32) | (base + (unsigned)i2);
    };

    auto merge_t = [&](int t) {
        if (tid < 64) {
            unsigned long long k0 = ~0ULL, k1 = ~0ULL, k2 = ~0ULL;
            #pragma unroll
            for (int q = 0; q < 8; ++q) {
                #pragma unroll
                for (int s = 0; s < 3; ++s) {
                    const unsigned long long k = s_key[tid][q * 3 + s];
                    const bool lt0 = k < k0, lt1 = k < k1, lt2 = k < k2;
                    k2 = lt1 ? k1 : (lt2 ? k : k2);
                    k1 = lt0 ? k0 : (lt1 ? k : k1);
                    k0 = lt0 ? k  : k0;
                }
            }
            const float e0 = __uint_as_float((unsigned)(k0 >> 32));
            const float e1 = __uint_as_float((unsigned)(k1 >> 32));
            const float e2 = __uint_as_float((unsigned)(k2 >> 32));
            const float m0 = fmaxf(e0, 1e-10f);
            const float m1 = fmaxf(e1, 1e-10f);
            const float m2 = fmaxf(e2, 1e-10f);
            float w0 = 1.0f / (m0 * m0 + 1e-10f);
            float w1 = 1.0f / (m1 * m1 + 1e-10f);
            float w2 = 1.0f / (m2 * m2 + 1e-10f);
            const int valid = masks[(size_t)b * N + nbase + t * 64 + tid] ? 1 : 0;
            const float scale = valid ? (1.0f / (w0 + w1 + w2)) : 0.0f;
            s_wt[t][tid][0] = w0 * scale;
            s_wt[t][tid][1] = w1 * scale;
            s_wt[t][tid][2] = w2 * scale;
            s_jv[t][tid][0] = (int)(unsigned)k0;
            s_jv[t][tid][1] = (int)(unsigned)k1;
            s_jv[t][tid][2] = (int)(unsigned)k2;
            s_jv[t][tid][3] = valid;
        }
    };

    // Pipelined phase-2 state (one row-group in flight per thread).
    float4 ga, gb, gc;
    float  ua, ub, uc;
    int    prow = 0, pval = 0;

    auto p2_issue = [&](int t, int i) {
        const int rg = tid >> 6;             // row-group = wave id
        const int cq = tid & 63;             // channel quad
        prow = i * 8 + rg;                   // wave-uniform row
        pval = __builtin_amdgcn_readfirstlane(s_jv[t][prow][3]);
        if (pval) {                          // scalar branch
            const int j0 = __builtin_amdgcn_readfirstlane(s_jv[t][prow][0]);
            const int j1 = __builtin_amdgcn_readfirstlane(s_jv[t][prow][1]);
            const int j2 = __builtin_amdgcn_readfirstlane(s_jv[t][prow][2]);
            ua = __uint_as_float((unsigned)
                __builtin_amdgcn_readfirstlane((int)__float_as_uint(s_wt[t][prow][0])));
            ub = __uint_as_float((unsigned)
                __builtin_amdgcn_readfirstlane((int)__float_as_uint(s_wt[t][prow][1])));
            uc = __uint_as_float((unsigned)
                __builtin_amdgcn_readfirstlane((int)__float_as_uint(s_wt[t][prow][2])));
            ga = Fb4[j0 * 64 + cq];
            gb = Fb4[j1 * 64 + cq];
            gc = Fb4[j2 * 64 + cq];
        }
    };

    auto p2_consume = [&](float4* op4t) {
        const int cq = tid & 63;
        float4 acc = make_float4(0.f, 0.f, 0.f, 0.f);
        if (pval) {
            acc.x = fmaf(uc, gc.x, fmaf(ub, gb.x, ua * ga.x));
            acc.y = fmaf(uc, gc.y, fmaf(ub, gb.y, ua * ga.y));
            acc.z = fmaf(uc, gc.z, fmaf(ub, gb.z, ua * ga.z));
            acc.w = fmaf(uc, gc.w, fmaf(ub, gb.w, ua * ga.w));
        }
        op4t[prow * 64 + cq] = acc;
    };

    // ---- Step 1: scan tile A (16 chunks x 8 candidates per wave) ----
    reset_ladder();
    for (int ch = 0; ch < 16; ++ch)
        scan_chunk(ch, x0, y0, z0);
    store_keys();
    __syncthreads();
    merge_t(0);
    __syncthreads();

    // ---- Step 2: FUSED p2(A) + scan(B) ----
    reset_ladder();
    p2_issue(0, 0);
    for (int i = 0; i < 8; ++i) {
        scan_chunk(2 * i,     x1, y1, z1);   // gathers in flight under ladder VALU
        scan_chunk(2 * i + 1, x1, y1, z1);
        p2_consume(op4_0);                   // gathers long since landed
        if (i < 7) p2_issue(0, i + 1);
    }
    store_keys();                            // tile B keys
    __syncthreads();
    merge_t(1);
    __syncthreads();

    // ---- Step 3: p2(B) (drain; TLP across 32 waves/CU hides latency) ----
    for (int i = 0; i < 8; ++i) {
        p2_issue(1, i);
        p2_consume(op4_1);
    }
}

extern "C" void kernel_launch(void* const* d_in, const int* in_sizes, int n_in,
                              void* d_out, int out_size, void* d_ws, size_t ws_size,
                              hipStream_t stream) {
    const float* xyz   = (const float*)d_in[0];
    const float* sxyz  = (const float*)d_in[1];
    const float* feats = (const float*)d_in[2];
    const int*   masks = (const int*)d_in[3];
    float*       out   = (float*)d_out;

    dim3 grid(B * N / 128);   // 1024 blocks
    dim3 block(512);
    hipLaunchKernelGGL(upsample_idw_kernel, grid, block, 0, stream,
                       xyz, sxyz, feats, masks, out);
}

// Round 14
// 76.990 us; speedup vs baseline: 1.0964x; 1.0173x over previous
//
#include <hip/hip_runtime.h>

// Problem constants (from reference setup_inputs).
constexpr int B = 8;
constexpr int N = 16384;
constexpr int M = 1024;
constexpr int C = 256;
constexpr int PTS = 64;   // points per block (lane l = point nbase+l)
constexpr int QW  = 4;    // candidate quarters (= waves per block)

typedef float vf16 __attribute__((ext_vector_type(16)));

// Prep: transpose sampled_xyz [B,M,3] -> SoA in d_ws: per batch,
// x[1024] | y[1024] | z[1024] (3072 floats/batch, 96KB total).
__global__ __launch_bounds__(256) void transpose_sxyz_kernel(
    const float* __restrict__ sxyz, float* __restrict__ ws)
{
    const int g = blockIdx.x * 256 + threadIdx.x;   // 0 .. B*M-1
    const int b = g >> 10, m = g & 1023;
    float* o = ws + b * 3072;
    const float* s = sxyz + (size_t)g * 3;
    o[m]        = s[0];
    o[1024 + m] = s[1];
    o[2048 + m] = s[2];
}

// Block = 256 threads = 4 waves, 2048 blocks (8/CU). Structure = r10 (66us)
// with ONE change: packed-f32 distance math (v_pk_add/mul_f32) on SoA
// candidates -> 2 candidates per VALU instr, 19 -> 15 ops/candidate.
// Bit-exactness: identical separately-rounded f32 sequence (dx*dx+dy*dy)+dz*dz
// per candidate ((c-x) squares identically to (x-c)); ladder unchanged
// (strict-< = top_k lowest-index tie-break; candidates processed in index order).
// XCD swizzle: batch = blk & 7 pins each batch's 1MB feats to one XCD's L2.
__global__ __launch_bounds__(256, 8) void upsample_idw_kernel(
    const float* __restrict__ xyz,          // [B,N,3]
    const float* __restrict__ ws,           // SoA candidates (from prep)
    const float* __restrict__ feats,        // [B,M,C]
    const int*   __restrict__ masks,        // [B,N]
    float*       __restrict__ out)          // [B,N,C]
{
    const int tid = threadIdx.x;
    const int w   = tid >> 6;               // wave id = candidate quarter
    const int l   = tid & 63;               // lane = point within block
    const int blk = blockIdx.x;
    const int b     = blk & 7;              // batch == XCD (round-robin dispatch)
    const int nbase = (blk >> 3) << 6;      // first point of this block

    __shared__ unsigned long long s_key[PTS][QW][3];   // 6KB
    __shared__ float s_w[PTS][3];
    __shared__ int   s_j[PTS][4];           // j0, j1, j2, valid

    // Own point coords (replicated across the 4 waves).
    const float* xp = xyz + ((size_t)b * N + nbase + l) * 3;
    const float x = xp[0], y = xp[1], z = xp[2];
    // Packed (x,x), (y,y), (z,z) for the pk ops.
    float2 px2; px2.x = x; px2.y = x;
    float2 py2; py2.x = y; py2.y = y;
    float2 pz2; pz2.x = z; pz2.y = z;

    // BLOCK-uniform SoA batch base; wave-quarter byte offset via readfirstlane.
    const float* wsbase = ws + (size_t)b * 3072;
    const int qoff = __builtin_amdgcn_readfirstlane((tid >> 6) * 1024); // 256 floats * 4B

    float d0 = __builtin_inff(), d1 = __builtin_inff(), d2 = __builtin_inff();
    int   i0 = 0, i1 = 0, i2 = 0;

    for (int ch = 0; ch < 16; ++ch) {       // 16 chunks x 16 candidates
        vf16 xs, ys, zs;                    // SoA: 16 x, 16 y, 16 z in SGPRs
        const int off = qoff + ch * 64;     // byte offset within x-array
        asm volatile(
            "s_load_dwordx16 %0, %3, %4\n\t"
            "s_load_dwordx16 %1, %3, %4 offset:0x1000\n\t"
            "s_load_dwordx16 %2, %3, %4 offset:0x2000\n\t"
            "s_waitcnt lgkmcnt(0)"
            : "=&s"(xs), "=&s"(ys), "=&s"(zs)
            : "s"(wsbase), "s"(off));
        #pragma unroll
        for (int j = 0; j < 8; ++j) {       // 8 pairs = 16 candidates
            float2 sx2; sx2.x = xs[2 * j]; sx2.y = xs[2 * j + 1];
            float2 sy2; sy2.x = ys[2 * j]; sy2.y = ys[2 * j + 1];
            float2 sz2; sz2.x = zs[2 * j]; sz2.y = zs[2 * j + 1];
            float2 d01, t0, t1;
            // Packed: d = (dx*dx + dy*dy) + dz*dz for 2 candidates at once.
            // v_pk_add/mul_f32 round identically to scalar IEEE f32 ops.
            asm("v_pk_add_f32 %1, %3, %6 neg_lo:[0,1] neg_hi:[0,1]\n\t"
                "v_pk_mul_f32 %1, %1, %1\n\t"
                "v_pk_add_f32 %2, %4, %7 neg_lo:[0,1] neg_hi:[0,1]\n\t"
                "v_pk_mul_f32 %2, %2, %2\n\t"
                "v_pk_add_f32 %1, %1, %2\n\t"
                "v_pk_add_f32 %2, %5, %8 neg_lo:[0,1] neg_hi:[0,1]\n\t"
                "v_pk_mul_f32 %2, %2, %2\n\t"
                "v_pk_add_f32 %0, %1, %2"
                : "=&v"(d01), "=&v"(t0), "=&v"(t1)
                : "s"(sx2), "s"(sy2), "s"(sz2),
                  "v"(px2), "v"(py2), "v"(pz2));
            // Ladder, candidate 2j first then 2j+1 (index order preserved).
            #pragma unroll
            for (int h = 0; h < 2; ++h) {
                const float d = (h == 0) ? d01.x : d01.y;
                const int m = ch * 16 + 2 * j + h;
                const bool lt0 = d < d0, lt1 = d < d1, lt2 = d < d2;
                i2 = lt1 ? i1 : (lt2 ? m : i2);
                i1 = lt0 ? i0 : (lt1 ? m : i1);
                i0 = lt0 ? m  : i0;
                const float nd2 = __builtin_amdgcn_fmed3f(d1, d2, d);
                const float nd1 = __builtin_amdgcn_fmed3f(d0, d1, d);
                d2 = nd2; d1 = nd1; d0 = fminf(d0, d);
            }
        }
    }

    // Pack (dist_bits, global_idx): monotone u64, lowest-index tie-break.
    const unsigned base = (unsigned)(w * 256);
    s_key[l][w][0] = ((unsigned long long)__float_as_uint(d0) << 32) | (base + (unsigned)i0);
    s_key[l][w][1] = ((unsigned long long)__float_as_uint(d1) << 32) | (base + (unsigned)i1);
    s_key[l][w][2] = ((unsigned long long)__float_as_uint(d2) << 32) | (base + (unsigned)i2);
    __syncthreads();

    // ---- Merge: 12 candidates -> top-3 (one thread per point) ----
    if (tid < PTS) {
        unsigned long long k0 = ~0ULL, k1 = ~0ULL, k2 = ~0ULL;
        #pragma unroll
        for (int q = 0; q < QW; ++q) {
            #pragma unroll
            for (int s = 0; s < 3; ++s) {
                const unsigned long long k = s_key[tid][q][s];
                const bool lt0 = k < k0, lt1 = k < k1, lt2 = k < k2;
                k2 = lt1 ? k1 : (lt2 ? k : k2);
                k1 = lt0 ? k0 : (lt1 ? k : k1);
                k0 = lt0 ? k  : k0;
            }
        }
        const float e0 = __uint_as_float((unsigned)(k0 >> 32));
        const float e1 = __uint_as_float((unsigned)(k1 >> 32));
        const float e2 = __uint_as_float((unsigned)(k2 >> 32));
        const float m0 = fmaxf(e0, 1e-10f);
        const float m1 = fmaxf(e1, 1e-10f);
        const float m2 = fmaxf(e2, 1e-10f);
        float w0 = 1.0f / (m0 * m0 + 1e-10f);
        float w1 = 1.0f / (m1 * m1 + 1e-10f);
        float w2 = 1.0f / (m2 * m2 + 1e-10f);
        const int valid = masks[(size_t)b * N + nbase + tid];
        const float scale = valid ? (1.0f / (w0 + w1 + w2)) : 0.0f;
        s_w[tid][0] = w0 * scale;
        s_w[tid][1] = w1 * scale;
        s_w[tid][2] = w2 * scale;
        s_j[tid][0] = (int)(unsigned)k0;
        s_j[tid][1] = (int)(unsigned)k1;
        s_j[tid][2] = (int)(unsigned)k2;
        s_j[tid][3] = valid;
    }
    __syncthreads();

    // ---- Phase 2: 4 points x 64 channel-quads per iteration ----
    const int pq = tid >> 6;                 // sub-point (= wave id)
    const int cq = tid & 63;                 // channel quad
    const float4* Fb4 = (const float4*)(feats + (size_t)b * (M * C));
    float4* op4 = (float4*)(out + (((size_t)b * N + nbase) * C));

    for (int p0 = 0; p0 < PTS; p0 += 4) {
        const int p = p0 + pq;               // wave-uniform
        const int vld = __builtin_amdgcn_readfirstlane(s_j[p][3]);
        float4 acc = make_float4(0.f, 0.f, 0.f, 0.f);
        if (vld) {                           // scalar branch
            const int j0 = __builtin_amdgcn_readfirstlane(s_j[p][0]);
            const int j1 = __builtin_amdgcn_readfirstlane(s_j[p][1]);
            const int j2 = __builtin_amdgcn_readfirstlane(s_j[p][2]);
            const float w0 = __uint_as_float(
                __builtin_amdgcn_readfirstlane((int)__float_as_uint(s_w[p][0])));
            const float w1 = __uint_as_float(
                __builtin_amdgcn_readfirstlane((int)__float_as_uint(s_w[p][1])));
            const float w2 = __uint_as_float(
                __builtin_amdgcn_readfirstlane((int)__float_as_uint(s_w[p][2])));
            const float4 f0 = Fb4[j0 * 64 + cq];
            const float4 f1 = Fb4[j1 * 64 + cq];
            const float4 f2 = Fb4[j2 * 64 + cq];
            acc.x = fmaf(w2, f2.x, fmaf(w1, f1.x, w0 * f0.x));
            acc.y = fmaf(w2, f2.y, fmaf(w1, f1.y, w0 * f0.y));
            acc.z = fmaf(w2, f2.z, fmaf(w1, f1.z, w0 * f0.z));
            acc.w = fmaf(w2, f2.w, fmaf(w1, f1.w, w0 * f0.w));
        }
        op4[p * 64 + cq] = acc;
    }
}

extern "C" void kernel_launch(void* const* d_in, const int* in_sizes, int n_in,
                              void* d_out, int out_size, void* d_ws, size_t ws_size,
                              hipStream_t stream) {
    const float* xyz   = (const float*)d_in[0];
    const float* sxyz  = (const float*)d_in[1];
    const float* feats = (const float*)d_in[2];
    const int*   masks = (const int*)d_in[3];
    float*       out   = (float*)d_out;
    float*       ws    = (float*)d_ws;       // 96KB SoA candidate buffer

    // Prep: SoA transpose (runs every call; deterministic).
    hipLaunchKernelGGL(transpose_sxyz_kernel, dim3(B * M / 256), dim3(256),
                       0, stream, sxyz, ws);

    dim3 grid(B * N / PTS);   // 2048 blocks
    dim3 block(256);
    hipLaunchKernelGGL(upsample_idw_kernel, grid, block, 0, stream,
                       xyz, ws, feats, masks, out);
}

// Round 15
// 66.617 us; speedup vs baseline: 1.2671x; 1.1557x over previous
//
#include <hip/hip_runtime.h>

// Problem constants (from reference setup_inputs).
constexpr int B = 8;
constexpr int N = 16384;
constexpr int M = 1024;
constexpr int C = 256;
constexpr int PTS = 64;   // points per block (lane l = point nbase+l)
constexpr int QW  = 4;    // candidate quarters (= waves per block)

typedef float vf16 __attribute__((ext_vector_type(16)));

// Block = 256 threads = 4 waves, 2048 blocks (8/CU, 32 waves/CU).
// Structure = r10 (66us, best) + ONE change: wave-uniform early-out around
// the select ladder. A candidate updates a lane's state iff d < d2 (strict <,
// so ties never update). If NO lane improves (ballot == 0, ~50% of iterations
// once d2 tightens), skip the 11-op ladder wholesale via a uniform branch.
// Inside the branch the ladder is the usual cndmask form, correct for all
// lanes (non-improving lanes keep state) -> selection is bit-identical.
// Phase 1 candidates come from SGPRs via s_load_dwordx16 (SMEM pipe, no LDS).
// Distance is bit-exact vs the reference: (dx*dx+dy*dy)+dz*dz, separately
// rounded; (c-x) squares identically to (x-c).
// XCD swizzle: batch = blk & 7 pins each batch's 1MB feats to one XCD's L2.
__global__ __launch_bounds__(256, 8) void upsample_idw_kernel(
    const float* __restrict__ xyz,          // [B,N,3]
    const float* __restrict__ sxyz,         // [B,M,3]
    const float* __restrict__ feats,        // [B,M,C]
    const int*   __restrict__ masks,        // [B,N]
    float*       __restrict__ out)          // [B,N,C]
{
    const int tid = threadIdx.x;
    const int w   = tid >> 6;               // wave id = candidate quarter
    const int l   = tid & 63;               // lane = point within block
    const int blk = blockIdx.x;
    const int b     = blk & 7;              // batch == XCD (round-robin dispatch)
    const int nbase = (blk >> 3) << 6;      // first point of this block

    __shared__ unsigned long long s_key[PTS][QW][3];   // 6KB
    __shared__ float s_w[PTS][3];
    __shared__ int   s_j[PTS][4];           // j0, j1, j2, valid

    // Own point coords (replicated across the 4 waves).
    const float* xp = xyz + ((size_t)b * N + nbase + l) * 3;
    const float x = xp[0], y = xp[1], z = xp[2];

    // BLOCK-uniform batch base (SGPR pair for s_load); wave-quarter byte
    // offset forced uniform via readfirstlane into the SMEM soffset operand.
    const float* bbase = sxyz + (size_t)b * (M * 3);
    const int qoff = __builtin_amdgcn_readfirstlane((tid >> 6) * (256 * 12));

    float d0 = __builtin_inff(), d1 = __builtin_inff(), d2 = __builtin_inff();
    int   i0 = 0, i1 = 0, i2 = 0;

    for (int ch = 0; ch < 16; ++ch) {       // 16 chunks x 16 candidates
        vf16 ca, cb, cc;                    // 48 floats = 16 candidates in SGPRs
        const int off = qoff + ch * 192;    // uniform byte offset
        asm volatile(
            "s_load_dwordx16 %0, %3, %4\n\t"
            "s_load_dwordx16 %1, %3, %4 offset:64\n\t"
            "s_load_dwordx16 %2, %3, %4 offset:128\n\t"
            "s_waitcnt lgkmcnt(0)"
            : "=&s"(ca), "=&s"(cb), "=&s"(cc)
            : "s"(bbase), "s"(off));
        #pragma unroll
        for (int j = 0; j < 16; ++j) {
            const int f0 = 3 * j, f1 = 3 * j + 1, f2 = 3 * j + 2;
            const float cx = (f0 < 16) ? ca[f0 & 15] : (f0 < 32) ? cb[f0 & 15] : cc[f0 & 15];
            const float cy = (f1 < 16) ? ca[f1 & 15] : (f1 < 32) ? cb[f1 & 15] : cc[f1 & 15];
            const float cz = (f2 < 16) ? ca[f2 & 15] : (f2 < 32) ? cb[f2 & 15] : cc[f2 & 15];
            // (c - x): negated dx, identical after squaring (IEEE exact).
            const float dx = __fsub_rn(cx, x);
            const float dy = __fsub_rn(cy, y);
            const float dz = __fsub_rn(cz, z);
            const float d  = __fadd_rn(__fadd_rn(__fmul_rn(dx, dx), __fmul_rn(dy, dy)),
                                       __fmul_rn(dz, dz));
            // Wave-uniform early-out: skip the ladder when NO lane improves.
            // d < d2 is exactly the "any state changes" predicate (strict <).
            if (__ballot(d < d2) != 0ULL) {
                const int m = ch * 16 + j;  // uniform value
                // Strict < keeps earlier (lower) index on ties (matches top_k).
                const bool lt0 = d < d0, lt1 = d < d1, lt2 = d < d2;
                i2 = lt1 ? i1 : (lt2 ? m : i2);
                i1 = lt0 ? i0 : (lt1 ? m : i1);
                i0 = lt0 ? m  : i0;
                // Exact value ladder: min + 2x med3 (selection only).
                const float nd2 = __builtin_amdgcn_fmed3f(d1, d2, d);
                const float nd1 = __builtin_amdgcn_fmed3f(d0, d1, d);
                d2 = nd2; d1 = nd1; d0 = fminf(d0, d);
            }
        }
    }

    // Pack (dist_bits, global_idx): monotone u64, lowest-index tie-break.
    const unsigned base = (unsigned)(w * 256);
    s_key[l][w][0] = ((unsigned long long)__float_as_uint(d0) << 32) | (base + (unsigned)i0);
    s_key[l][w][1] = ((unsigned long long)__float_as_uint(d1) << 32) | (base + (unsigned)i1);
    s_key[l][w][2] = ((unsigned long long)__float_as_uint(d2) << 32) | (base + (unsigned)i2);
    __syncthreads();

    // ---- Merge: 12 candidates -> top-3 (one thread per point) ----
    if (tid < PTS) {
        unsigned long long k0 = ~0ULL, k1 = ~0ULL, k2 = ~0ULL;
        #pragma unroll
        for (int q = 0; q < QW; ++q) {
            #pragma unroll
            for (int s = 0; s < 3; ++s) {
                const unsigned long long k = s_key[tid][q][s];
                const bool lt0 = k < k0, lt1 = k < k1, lt2 = k < k2;
                k2 = lt1 ? k1 : (lt2 ? k : k2);
                k1 = lt0 ? k0 : (lt1 ? k : k1);
                k0 = lt0 ? k  : k0;
            }
        }
        const float e0 = __uint_as_float((unsigned)(k0 >> 32));
        const float e1 = __uint_as_float((unsigned)(k1 >> 32));
        const float e2 = __uint_as_float((unsigned)(k2 >> 32));
        const float m0 = fmaxf(e0, 1e-10f);
        const float m1 = fmaxf(e1, 1e-10f);
        const float m2 = fmaxf(e2, 1e-10f);
        float w0 = 1.0f / (m0 * m0 + 1e-10f);
        float w1 = 1.0f / (m1 * m1 + 1e-10f);
        float w2 = 1.0f / (m2 * m2 + 1e-10f);
        const int valid = masks[(size_t)b * N + nbase + tid];
        const float scale = valid ? (1.0f / (w0 + w1 + w2)) : 0.0f;
        s_w[tid][0] = w0 * scale;
        s_w[tid][1] = w1 * scale;
        s_w[tid][2] = w2 * scale;
        s_j[tid][0] = (int)(unsigned)k0;
        s_j[tid][1] = (int)(unsigned)k1;
        s_j[tid][2] = (int)(unsigned)k2;
        s_j[tid][3] = valid;
    }
    __syncthreads();

    // ---- Phase 2: 4 points x 64 channel-quads per iteration ----
    const int pq = tid >> 6;                 // sub-point (= wave id)
    const int cq = tid & 63;                 // channel quad
    const float4* Fb4 = (const float4*)(feats + (size_t)b * (M * C));
    float4* op4 = (float4*)(out + (((size_t)b * N + nbase) * C));

    for (int p0 = 0; p0 < PTS; p0 += 4) {
        const int p = p0 + pq;               // wave-uniform
        const int vld = __builtin_amdgcn_readfirstlane(s_j[p][3]);
        float4 acc = make_float4(0.f, 0.f, 0.f, 0.f);
        if (vld) {                           // scalar branch
            const int j0 = __builtin_amdgcn_readfirstlane(s_j[p][0]);
            const int j1 = __builtin_amdgcn_readfirstlane(s_j[p][1]);
            const int j2 = __builtin_amdgcn_readfirstlane(s_j[p][2]);
            const float w0 = __uint_as_float(
                __builtin_amdgcn_readfirstlane((int)__float_as_uint(s_w[p][0])));
            const float w1 = __uint_as_float(
                __builtin_amdgcn_readfirstlane((int)__float_as_uint(s_w[p][1])));
            const float w2 = __uint_as_float(
                __builtin_amdgcn_readfirstlane((int)__float_as_uint(s_w[p][2])));
            const float4 f0 = Fb4[j0 * 64 + cq];
            const float4 f1 = Fb4[j1 * 64 + cq];
            const float4 f2 = Fb4[j2 * 64 + cq];
            acc.x = fmaf(w2, f2.x, fmaf(w1, f1.x, w0 * f0.x));
            acc.y = fmaf(w2, f2.y, fmaf(w1, f1.y, w0 * f0.y));
            acc.z = fmaf(w2, f2.z, fmaf(w1, f1.z, w0 * f0.z));
            acc.w = fmaf(w2, f2.w, fmaf(w1, f1.w, w0 * f0.w));
        }
        op4[p * 64 + cq] = acc;
    }
}

extern "C" void kernel_launch(void* const* d_in, const int* in_sizes, int n_in,
                              void* d_out, int out_size, void* d_ws, size_t ws_size,
                              hipStream_t stream) {
    const float* xyz   = (const float*)d_in[0];
    const float* sxyz  = (const float*)d_in[1];
    const float* feats = (const float*)d_in[2];
    const int*   masks = (const int*)d_in[3];
    float*       out   = (float*)d_out;

    dim3 grid(B * N / PTS);   // 2048 blocks
    dim3 block(256);
    hipLaunchKernelGGL(upsample_idw_kernel, grid, block, 0, stream,
                       xyz, sxyz, feats, masks, out);
}